// Round 13
// baseline (476.064 us; speedup 1.0000x reference)
//
#include <hip/hip_runtime.h>
#include <math.h>

typedef _Float16 f16;
typedef _Float16 f16x8 __attribute__((ext_vector_type(8)));
typedef float f32x4 __attribute__((ext_vector_type(4)));

#define T_ 8
#define NNODES 100000
#define F_ 128
#define B_ 4096
#define S1_ 5
#define S2_ 2
#define H1_ 512
#define H2_ 64
#define O_ 32
#define M1 (B_ + B_*S1_)      /* 24576 rows: [h0-block | h1-block] */
#define K1 (2*F_)             /* 256: [h | agg] */
#define NZ 12                 /* z<8 -> (t=z,c=0); z>=8 -> (t=2*(z-8),c=1) */

__device__ __forceinline__ float wsum64(float v) {
#pragma unroll
  for (int o = 32; o > 0; o >>= 1) v += __shfl_xor(v, o, 64);
  return v;
}

// ---------------------------------------------------------------- pos table
__global__ __launch_bounds__(512) void postab_kernel(float* __restrict__ postab) {
  int i = threadIdx.x;
  int p = i >> 6, d = i & 63;
  double ang = (double)p / pow(10000.0, (2.0 * (double)(d >> 1)) / 64.0);
  postab[i] = (float)((d & 1) ? cos(ang) : sin(ang));
}

// ---------------------------------------------------------------- gemm1 weight limbs
// FRAGMENT-TILE layout: 16B unit (c, ntile=n>>4, kt=k>>5, lane=kg*16+lr)
// holds B[c][n=ntile*16+lr][k=kt*32+kg*8 .. +8]. A wave's frag load is one
// contiguous 1KB run (uniform base + lane*16).
__global__ __launch_bounds__(256)
void prep_w(const float* __restrict__ Ws1, const float* __restrict__ Wn1,
            f16* __restrict__ Bth, f16* __restrict__ Btl) {
  const int bid = blockIdx.x;            // 0..1023
  const int c = bid >> 9, n = bid & 511;
  const int k = threadIdx.x;             // 0..255
  float wv = (k < F_) ? Ws1[((size_t)c * F_ + k) * H1_ + n]
                      : Wn1[((size_t)c * F_ + (k - F_)) * H1_ + n];
  f16 hi = (f16)wv;
  f16 lo = (f16)((wv - (float)hi) * 2048.0f);
  const int ntile = n >> 4, lr = n & 15;
  const int kt = k >> 5, kg = (k >> 3) & 3, ke = k & 7;
  size_t o = ((((size_t)c * 32 + ntile) * 8 + kt) * 64 + kg * 16 + lr) * 8 + ke;
  Bth[o] = hi; Btl[o] = lo;
}

// ---------------------------------------------------------------- gemm2 weight limbs
__global__ __launch_bounds__(256)
void prep_w2(const float* __restrict__ Ws2, const float* __restrict__ Wn2,
             f16* __restrict__ B2h, f16* __restrict__ B2l) {
  const int c = blockIdx.x >> 6, n = blockIdx.x & 63;
#pragma unroll
  for (int q = 0; q < 4; ++q) {
    const int k = q * 256 + threadIdx.x;
    float v = (k < H1_) ? Ws2[((size_t)c * H1_ + k) * H2_ + n]
                        : 0.2f * Wn2[((size_t)c * H1_ + (k - H1_)) * H2_ + n];
    f16 hi = (f16)v;
    f16 lo = (f16)((v - (float)hi) * 2048.0f);
    size_t o = ((size_t)c * H2_ + n) * 1024 + k;
    B2h[o] = hi; B2l[o] = lo;
  }
}

// ---------------------------------------------------------------- gather+agg
__global__ __launch_bounds__(256) void gather_kernel(
    const int* __restrict__ nodes, const int* __restrict__ hop1,
    const int* __restrict__ hop2, const float* __restrict__ x,
    f16* __restrict__ Ah, f16* __restrict__ Al)
{
  const int t = blockIdx.y;
  const int r = blockIdx.x * 4 + (threadIdx.x >> 6);
  const int lane = threadIdx.x & 63;
  const int fo = (lane & 31) << 2;
  const bool hpart = lane < 32;
  const float* xt = x + (size_t)t * NNODES * F_;
  float4 v;
  if (r < B_) {
    if (hpart) {
      v = *(const float4*)(xt + (size_t)nodes[r] * F_ + fo);
    } else {
      v = make_float4(0.f, 0.f, 0.f, 0.f);
#pragma unroll
      for (int s = 0; s < S1_; ++s) {
        int idx = hop1[t * (B_ * S1_) + r * S1_ + s];
        float4 u = *(const float4*)(xt + (size_t)idx * F_ + fo);
        v.x += u.x; v.y += u.y; v.z += u.z; v.w += u.w;
      }
      v.x /= 5.0f; v.y /= 5.0f; v.z /= 5.0f; v.w /= 5.0f;
    }
  } else {
    const int j = r - B_;
    if (hpart) {
      v = *(const float4*)(xt + (size_t)hop1[t * (B_ * S1_) + j] * F_ + fo);
    } else {
      v = make_float4(0.f, 0.f, 0.f, 0.f);
#pragma unroll
      for (int s = 0; s < S2_; ++s) {
        int idx = hop2[t * (B_ * S1_ * S2_) + j * S2_ + s];
        float4 u = *(const float4*)(xt + (size_t)idx * F_ + fo);
        v.x += u.x; v.y += u.y; v.z += u.z; v.w += u.w;
      }
      v.x *= 0.5f; v.y *= 0.5f; v.z *= 0.5f; v.w *= 0.5f;
    }
  }
  union { f16 h[4]; uint2 u; } H, L;
  float vv[4] = {v.x, v.y, v.z, v.w};
#pragma unroll
  for (int e = 0; e < 4; ++e) {
    f16 hi = (f16)vv[e];
    H.h[e] = hi;
    L.h[e] = (f16)((vv[e] - (float)hi) * 2048.0f);
  }
  const size_t base = ((size_t)t * M1 + r) * K1 + 4 * lane;
  *(uint2*)(Ah + base) = H.u;
  *(uint2*)(Al + base) = L.u;
}

// ---------------------------------------------------------------- GEMM1 (MFMA fp16x3) + spike
// 256x128 tile, 512 thr (8 waves), BK=32. A staged via global_load_lds into
// 3-buffer LDS (96 KB) with R11's proven paired-sync depth-2 pipeline.
// B loaded DIRECT global->reg from fragment-tile layout (1KB coalesced wave
// loads, L2-resident, register double-buffered one kt ahead; register-dep
// waits -> deterministic). LDS read traffic halved vs R11.
__global__ __launch_bounds__(512)
void gemm1_mfma(const f16* __restrict__ Ah, const f16* __restrict__ Al,
                const f16* __restrict__ Bth, const f16* __restrict__ Btl,
                unsigned char* __restrict__ Sbase)
{
  // bijective XCD swizzle: 4608 blocks = 8 XCDs x 576.
  const int hid = blockIdx.x + 4 * blockIdx.y + 384 * blockIdx.z;
  const int xcd = hid & 7, ii = hid >> 3;   // ii 0..575
  const int nblk = ii & 3;
  const int pair = xcd * 144 + (ii >> 2);   // 0..1151 = (yblk,z)
  const int yblk = pair % 96;
  const int z    = pair / 96;

  const int t = (z < 8) ? z : 2 * (z - 8);
  const int c = (z < 8) ? 0 : 1;
  const int m0 = yblk * 256;
  const int tid = threadIdx.x;
  const int lane = tid & 63;
  const int w = tid >> 6;                   // 0..7
  const int wr = w >> 1, wc = w & 1;        // wave tile (wr*64, wc*64)

  // A-only buffers: Ah rows[0,256) @0, Al @8192 (f16 units); row stride 32.
  // 16B unit (row,kcs) holds global chunk kc = kcs^(row&3).
  __shared__ f16 lds[3][16384];             // 96 KB

  const f16* tbAh = Ah + (size_t)t * M1 * K1;
  const f16* tbAl = Al + (size_t)t * M1 * K1;

  // staging unit u = q*512 + tid in [0,2048): LDS byte = u*16.
  const f16* srcp[4];
#pragma unroll
  for (int q = 0; q < 4; ++q) {
    const int u = q * 512 + tid;
    const f16* base = (u < 1024) ? tbAh : tbAl;
    const int row = (u & 1023) >> 2;
    const int kc = (u & 3) ^ (row & 3);
    srcp[q] = base + (size_t)(m0 + row) * K1 + kc * 8;
  }

  auto stage = [&](int buf) {
#pragma unroll
    for (int q = 0; q < 4; ++q) {
      __builtin_amdgcn_global_load_lds(
          (const __attribute__((address_space(1))) void*)srcp[q],
          (__attribute__((address_space(3))) void*)((char*)lds + buf * 32768 + (q * 8 + w) * 1024),
          16, 0, 0);
      srcp[q] += 32;   // next BK=32 chunk
    }
  };

  // B fragment base pointers (frag j, kt advances by 512 f16)
  const f16* pBh[4];
  const f16* pBl[4];
#pragma unroll
  for (int j = 0; j < 4; ++j) {
    const int ntile = nblk * 8 + wc * 4 + j;
    const size_t bo = (((size_t)c * 32 + ntile) * 8) * 512 + lane * 8;
    pBh[j] = Bth + bo;
    pBl[j] = Btl + bo;
  }

  f32x4 accm[4][4], accc[4][4];
#pragma unroll
  for (int i = 0; i < 4; ++i)
#pragma unroll
    for (int j = 0; j < 4; ++j) {
      accm[i][j] = (f32x4){0.f, 0.f, 0.f, 0.f};
      accc[i][j] = (f32x4){0.f, 0.f, 0.f, 0.f};
    }

  const int kg = lane >> 4;            // k-group 0..3
  const int lr = lane & 15;
  const int ks = (kg ^ (lr & 3)) * 8;  // swizzled k-slot (f16 units)

  f16x8 bH[2][4], bL[2][4];
#pragma unroll
  for (int j = 0; j < 4; ++j) {        // B for kt=0
    bH[0][j] = *(const f16x8*)(pBh[j]);
    bL[0][j] = *(const f16x8*)(pBl[j]);
  }

  stage(0);
  stage(1);
  __syncthreads();

#pragma unroll
  for (int kt = 0; kt < 8; ++kt) {
    const int cur = kt % 3;
    const int pb = kt & 1;
    const f16* bufp = &lds[cur][0];

    // phase 1: ah reads; A-stage depth-2; B prefetch kt+1; MFMA accm
    f16x8 ah[4];
#pragma unroll
    for (int i = 0; i < 4; ++i) ah[i] = *(const f16x8*)(bufp + (wr * 64 + i * 16 + lr) * 32 + ks);
    if (kt < 6) stage((kt + 2) % 3);
    if (kt < 7) {
#pragma unroll
      for (int j = 0; j < 4; ++j) {
        bH[pb ^ 1][j] = *(const f16x8*)(pBh[j] + (kt + 1) * 512);
        bL[pb ^ 1][j] = *(const f16x8*)(pBl[j] + (kt + 1) * 512);
      }
    }
    __builtin_amdgcn_s_setprio(1);
#pragma unroll
    for (int j = 0; j < 4; ++j)
#pragma unroll
      for (int i = 0; i < 4; ++i)
        accm[i][j] = __builtin_amdgcn_mfma_f32_16x16x32_f16(ah[i], bH[pb][j], accm[i][j], 0, 0, 0);
    __builtin_amdgcn_s_setprio(0);

    // phase 2: MFMA accc += ah*bl
    __builtin_amdgcn_s_setprio(1);
#pragma unroll
    for (int j = 0; j < 4; ++j)
#pragma unroll
      for (int i = 0; i < 4; ++i)
        accc[i][j] = __builtin_amdgcn_mfma_f32_16x16x32_f16(ah[i], bL[pb][j], accc[i][j], 0, 0, 0);
    __builtin_amdgcn_s_setprio(0);

    // phase 3: al reads; MFMA accc += al*bh
    f16x8 al[4];
#pragma unroll
    for (int i = 0; i < 4; ++i) al[i] = *(const f16x8*)(bufp + 8192 + (wr * 64 + i * 16 + lr) * 32 + ks);
    __builtin_amdgcn_s_setprio(1);
#pragma unroll
    for (int j = 0; j < 4; ++j)
#pragma unroll
      for (int i = 0; i < 4; ++i)
        accc[i][j] = __builtin_amdgcn_mfma_f32_16x16x32_f16(al[i], bH[pb][j], accc[i][j], 0, 0, 0);
    __builtin_amdgcn_s_setprio(0);

    // boundary: odd kt -> full drain (certifies tiles kt+1, kt+2);
    // even kt (<6) -> raw barrier (read-protection only).
    if (kt == 1 || kt == 3 || kt == 5) {
      __syncthreads();
    } else if (kt == 0 || kt == 2 || kt == 4) {
      asm volatile("s_waitcnt lgkmcnt(0)" ::: "memory");
      __builtin_amdgcn_s_barrier();
      __builtin_amdgcn_sched_barrier(0);
    }
  }

  // epilogue: v = accm + accc * 2^-11 ; spike >= 1.0
  // C/D (16x16, m89-verified): col = lane&15, row = (lane>>4)*4 + r
  const int n0 = nblk * 128;
  unsigned char* S = Sbase + (size_t)z * M1 * H1_;
#pragma unroll
  for (int i = 0; i < 4; ++i)
#pragma unroll
    for (int j = 0; j < 4; ++j) {
      const int n = n0 + wc * 64 + j * 16 + lr;
#pragma unroll
      for (int r = 0; r < 4; ++r) {
        const int m = m0 + wr * 64 + i * 16 + kg * 4 + r;
        float v = accm[i][j][r] + accc[i][j][r] * 4.8828125e-4f;
        S[(size_t)m * H1_ + n] = (v >= 1.0f) ? 1 : 0;
      }
    }
}

// ---------------------------------------------------------------- GEMM2 fused (S -> A-tile in-kernel) + spike
__global__ __launch_bounds__(256)
void gemm2_fused(const unsigned char* __restrict__ Sbase,
                 const f16* __restrict__ B2h, const f16* __restrict__ B2l,
                 unsigned char* __restrict__ outsbase)
{
  const int z = blockIdx.y;
  const int c = (z < 8) ? 0 : 1;
  const int m0 = blockIdx.x * 128;
  const int tid = threadIdx.x;
  const int lane = tid & 63;
  const int wv = tid >> 6;

  __shared__ f16 lds2[2][8192];   // [buf][A:4096 | Bh:2048 | Bl:2048] f16 = 32 KB

  const unsigned char* Sz = Sbase + (size_t)z * M1 * H1_;
  const f16* Bhc = B2h + (size_t)c * H2_ * 1024;
  const f16* Blc = B2l + (size_t)c * H2_ * 1024;

  const f16* srcB[2];
#pragma unroll
  for (int q = 0; q < 2; ++q) {
    const int v = q * 256 + tid;              // 0..511
    if (v < 256) {
      const int k8 = v >> 6, row = v & 63;
      srcB[q] = Bhc + (size_t)row * 1024 + k8 * 8;
    } else {
      const int v2 = v - 256, k8 = v2 >> 6, row = v2 & 63;
      srcB[q] = Blc + (size_t)row * 1024 + k8 * 8;
    }
  }
  auto stageB = [&](int buf) {
#pragma unroll
    for (int q = 0; q < 2; ++q) {
      __builtin_amdgcn_global_load_lds(
          (const __attribute__((address_space(1))) void*)srcB[q],
          (__attribute__((address_space(3))) void*)((char*)lds2 + buf * 16384 + 8192 + q * 4096 + wv * 1024),
          16, 0, 0);
      srcB[q] += 32;
    }
  };

  const int arow = tid >> 1;       // 0..127
  const int ahalf = tid & 1;
  const int k8b = ahalf * 2;

  auto loadS = [&](int kt, uint4* regs) {
    if (kt < 16) {
      regs[0] = *(const uint4*)(Sz + (size_t)(m0 + arow) * H1_ + kt * 32 + ahalf * 16);
    } else {
      const int k0 = (kt - 16) * 32 + ahalf * 16;
#pragma unroll
      for (int s = 0; s < S1_; ++s)
        regs[s] = *(const uint4*)(Sz + ((size_t)B_ + (size_t)(m0 + arow) * S1_ + s) * H1_ + k0);
    }
  };
  auto writeA = [&](int buf, int kt, const uint4* regs) {
    uint4 b;
    if (kt < 16) {
      b = regs[0];
    } else {
      b.x = regs[0].x + regs[1].x + regs[2].x + regs[3].x + regs[4].x;
      b.y = regs[0].y + regs[1].y + regs[2].y + regs[3].y + regs[4].y;
      b.z = regs[0].z + regs[1].z + regs[2].z + regs[3].z + regs[4].z;
      b.w = regs[0].w + regs[1].w + regs[2].w + regs[3].w + regs[4].w;
    }
    union { uint4 v; unsigned char by[16]; } U; U.v = b;
    union { f16 h[8]; uint4 v; } P0, P1;
#pragma unroll
    for (int e = 0; e < 8; ++e) {
      P0.h[e] = (f16)(int)U.by[e];
      P1.h[e] = (f16)(int)U.by[8 + e];
    }
    f16* dst = &lds2[buf][0];
    *(uint4*)(dst + ((size_t)k8b * 128 + arow) * 8)       = P0.v;
    *(uint4*)(dst + ((size_t)(k8b + 1) * 128 + arow) * 8) = P1.v;
  };

  f32x4 acch[2][4], accl[2][4];
#pragma unroll
  for (int i = 0; i < 2; ++i)
#pragma unroll
    for (int j = 0; j < 4; ++j) {
      acch[i][j] = (f32x4){0.f, 0.f, 0.f, 0.f};
      accl[i][j] = (f32x4){0.f, 0.f, 0.f, 0.f};
    }

  const int kg = lane >> 4;
  const int lr = lane & 15;

  {
    uint4 regs[5];
    loadS(0, regs);
    stageB(0);
    writeA(0, 0, regs);
  }
  __syncthreads();

#pragma unroll 1
  for (int kt = 0; kt < 32; ++kt) {
    const int cur = kt & 1;
    uint4 regs[5];
    if (kt < 31) {
      stageB(cur ^ 1);
      loadS(kt + 1, regs);
    }

    f16x8 a[2];
#pragma unroll
    for (int i = 0; i < 2; ++i)
      a[i] = *(const f16x8*)&lds2[cur][(size_t)(kg * 128 + wv * 32 + i * 16 + lr) * 8];
#pragma unroll
    for (int j = 0; j < 4; ++j) {
      f16x8 bh = *(const f16x8*)&lds2[cur][4096 + (size_t)(kg * 64 + j * 16 + lr) * 8];
      f16x8 bl = *(const f16x8*)&lds2[cur][6144 + (size_t)(kg * 64 + j * 16 + lr) * 8];
#pragma unroll
      for (int i = 0; i < 2; ++i) {
        acch[i][j] = __builtin_amdgcn_mfma_f32_16x16x32_f16(a[i], bh, acch[i][j], 0, 0, 0);
        accl[i][j] = __builtin_amdgcn_mfma_f32_16x16x32_f16(a[i], bl, accl[i][j], 0, 0, 0);
      }
    }
    if (kt < 31) writeA(cur ^ 1, kt + 1, regs);
    __syncthreads();
  }

  unsigned char* outs = outsbase + (size_t)z * B_ * H2_;
#pragma unroll
  for (int i = 0; i < 2; ++i)
#pragma unroll
    for (int j = 0; j < 4; ++j) {
      const int n = j * 16 + lr;
#pragma unroll
      for (int r = 0; r < 4; ++r) {
        const int m = m0 + wv * 32 + i * 16 + kg * 4 + r;
        float v = acch[i][j][r] + accl[i][j][r] * 4.8828125e-4f;
        outs[(size_t)m * H2_ + n] = (v >= 1.0f) ? 1 : 0;
      }
    }
}

// ---------------------------------------------------------------- attention + head
__global__ __launch_bounds__(256)
void final_kernel(const unsigned char* __restrict__ outsbase,
                  const float* __restrict__ postab,
                  const float* __restrict__ apw, const float* __restrict__ apb,
                  const float* __restrict__ anw, const float* __restrict__ anb,
                  const float* __restrict__ mtgw, const float* __restrict__ mtgb,
                  float* __restrict__ out)
{
  const int b = blockIdx.x * 4 + (threadIdx.x >> 6);
  const int lane = threadIdx.x & 63;
  float stacked = 0.f;
#pragma unroll
  for (int c = 0; c < 2; ++c) {
    const int Tc = c ? 4 : 8;
    const int zb = c ? 8 : 0;
    const float wp = apw[c * H2_ + lane];
    const float wn = anw[c * H2_ + lane];
    float seqv[8], sp[8], sn[8];
#pragma unroll
    for (int tt = 0; tt < Tc; ++tt) {
      const float sv = (float)outsbase[((size_t)(zb + tt) * B_ + b) * H2_ + lane];
      seqv[tt] = sv;
      sp[tt] = wsum64((sv + postab[tt * H2_ + lane]) * wp);
      sn[tt] = wsum64(sv * wn);
    }
    const float bp = apb[c], bn = anb[c];
    float mp = -3.4e38f, mn = -3.4e38f;
#pragma unroll
    for (int tt = 0; tt < Tc; ++tt) {
      sp[tt] += bp; sn[tt] += bn;
      mp = fmaxf(mp, sp[tt]); mn = fmaxf(mn, sn[tt]);
    }
    float ep[8], en[8], sump = 0.f, sumn = 0.f;
#pragma unroll
    for (int tt = 0; tt < Tc; ++tt) {
      ep[tt] = expf(sp[tt] - mp);
      en[tt] = expf(sn[tt] - mn);
      sump += ep[tt]; sumn += en[tt];
    }
    float embp = 0.f, embn = 0.f;
#pragma unroll
    for (int tt = 0; tt < Tc; ++tt) {
      embp += (seqv[tt] + postab[tt * H2_ + lane]) * (ep[tt] / sump);
      embn += seqv[tt] * (en[tt] / sumn);
    }
    stacked += 0.5f * (0.6f * embp + 0.4f * embn);
  }
  float res = 0.f;
#pragma unroll
  for (int o = 0; o < O_; ++o) {
    float r = wsum64(stacked * mtgw[lane * O_ + o]);
    if (lane == o) res = r;
  }
  if (lane < O_) out[(size_t)b * O_ + lane] = res + mtgb[lane];
}

// ---------------------------------------------------------------- launch
extern "C" void kernel_launch(void* const* d_in, const int* in_sizes, int n_in,
                              void* d_out, int out_size, void* d_ws, size_t ws_size,
                              hipStream_t stream)
{
  const int*   nodes  = (const int*)d_in[0];
  const int*   hop1   = (const int*)d_in[1];
  const int*   hop2   = (const int*)d_in[2];
  const float* x      = (const float*)d_in[3];
  const float* Wself1 = (const float*)d_in[4];
  const float* Wnbr1  = (const float*)d_in[5];
  const float* Wself2 = (const float*)d_in[6];
  const float* Wnbr2  = (const float*)d_in[7];
  const float* apw    = (const float*)d_in[8];
  const float* apb    = (const float*)d_in[9];
  const float* anw    = (const float*)d_in[10];
  const float* anb    = (const float*)d_in[11];
  const float* mtgw   = (const float*)d_in[12];
  const float* mtgb   = (const float*)d_in[13];
  float* out = (float*)d_out;

  char* ws = (char*)d_ws;
  size_t off = 0;
  float* postab = (float*)(ws + off);               off += 4096;
  f16* Ahb = (f16*)(ws + off);                      off += (size_t)T_ * M1 * K1 * 2;  // 100.66 MB
  f16* Alb = (f16*)(ws + off);                      off += (size_t)T_ * M1 * K1 * 2;  // 100.66 MB
  unsigned char* Sbase = (unsigned char*)(ws + off); off += (size_t)NZ * M1 * H1_;    // 151.0 MB
  unsigned char* outsb = (unsigned char*)(ws + off); off += (size_t)NZ * B_ * H2_;    //   3.1 MB
  if (ws_size < off) return;

  // stream-ordered aliases:
  //  - gemm1 B limbs (fragment-tile layout, 512KB+512KB) live in outsb until
  //    gemm2 overwrites outs (1.0 MB < 3.1 MB)
  //  - B2t limbs (512 KB) reuse Alb after gemm1 (prep_w2 launches after gemm1)
  f16* Bth = (f16*)outsb;
  f16* Btl = Bth + (size_t)2 * H1_ * K1;
  f16* B2h = Alb;
  f16* B2l = B2h + (size_t)2 * H2_ * 1024;

  hipLaunchKernelGGL(postab_kernel, dim3(1), dim3(512), 0, stream, postab);
  hipLaunchKernelGGL(prep_w, dim3(1024), dim3(256), 0, stream, Wself1, Wnbr1, Bth, Btl);
  hipLaunchKernelGGL(gather_kernel, dim3(M1 / 4, T_), dim3(256), 0, stream,
                     nodes, hop1, hop2, x, Ahb, Alb);
  hipLaunchKernelGGL(gemm1_mfma, dim3(4, 96, NZ), dim3(512), 0, stream,
                     Ahb, Alb, Bth, Btl, Sbase);
  hipLaunchKernelGGL(prep_w2, dim3(128), dim3(256), 0, stream, Wself2, Wnbr2, B2h, B2l);
  hipLaunchKernelGGL(gemm2_fused, dim3(B_ / 128, NZ), dim3(256), 0, stream,
                     Sbase, B2h, B2l, outsb);
  hipLaunchKernelGGL(final_kernel, dim3(B_ / 4), dim3(256), 0, stream,
                     outsb, postab, apw, apb, anw, anb, mtgw, mtgb, out);
}

// Round 14
// 457.886 us; speedup vs baseline: 1.0397x; 1.0397x over previous
//
#include <hip/hip_runtime.h>
#include <math.h>

typedef _Float16 f16;
typedef _Float16 f16x8 __attribute__((ext_vector_type(8)));
typedef float f32x4 __attribute__((ext_vector_type(4)));

#define T_ 8
#define NNODES 100000
#define F_ 128
#define B_ 4096
#define S1_ 5
#define S2_ 2
#define H1_ 512
#define H2_ 64
#define O_ 32
#define M1 (B_ + B_*S1_)      /* 24576 rows: [h0-block | h1-block] */
#define K1 (2*F_)             /* 256: [h | agg] */
#define NZ 12                 /* z<8 -> (t=z,c=0); z>=8 -> (t=2*(z-8),c=1) */

__device__ __forceinline__ float wsum64(float v) {
#pragma unroll
  for (int o = 32; o > 0; o >>= 1) v += __shfl_xor(v, o, 64);
  return v;
}

// ---------------------------------------------------------------- pos table
__global__ __launch_bounds__(512) void postab_kernel(float* __restrict__ postab) {
  int i = threadIdx.x;
  int p = i >> 6, d = i & 63;
  double ang = (double)p / pow(10000.0, (2.0 * (double)(d >> 1)) / 64.0);
  postab[i] = (float)((d & 1) ? cos(ang) : sin(ang));
}

// ---------------------------------------------------------------- gemm1 weight limbs
// Bt[c][n=512][k=256] f16; k<128 from Wself1, k>=128 from Wnbr1 (transposed)
__global__ __launch_bounds__(256)
void prep_w(const float* __restrict__ Ws1, const float* __restrict__ Wn1,
            f16* __restrict__ Bth, f16* __restrict__ Btl) {
  const int bid = blockIdx.x;            // 0..1023
  const int c = bid >> 9, n = bid & 511;
  const int k = threadIdx.x;             // 0..255
  float wv = (k < F_) ? Ws1[((size_t)c * F_ + k) * H1_ + n]
                      : Wn1[((size_t)c * F_ + (k - F_)) * H1_ + n];
  f16 hi = (f16)wv;
  f16 lo = (f16)((wv - (float)hi) * 2048.0f);
  size_t o = ((size_t)c * H1_ + n) * K1 + k;
  Bth[o] = hi; Btl[o] = lo;
}

// ---------------------------------------------------------------- gemm2 weight limbs
__global__ __launch_bounds__(256)
void prep_w2(const float* __restrict__ Ws2, const float* __restrict__ Wn2,
             f16* __restrict__ B2h, f16* __restrict__ B2l) {
  const int c = blockIdx.x >> 6, n = blockIdx.x & 63;
#pragma unroll
  for (int q = 0; q < 4; ++q) {
    const int k = q * 256 + threadIdx.x;
    float v = (k < H1_) ? Ws2[((size_t)c * H1_ + k) * H2_ + n]
                        : 0.2f * Wn2[((size_t)c * H1_ + (k - H1_)) * H2_ + n];
    f16 hi = (f16)v;
    f16 lo = (f16)((v - (float)hi) * 2048.0f);
    size_t o = ((size_t)c * H2_ + n) * 1024 + k;
    B2h[o] = hi; B2l[o] = lo;
  }
}

// ---------------------------------------------------------------- gather+agg
__global__ __launch_bounds__(256) void gather_kernel(
    const int* __restrict__ nodes, const int* __restrict__ hop1,
    const int* __restrict__ hop2, const float* __restrict__ x,
    f16* __restrict__ Ah, f16* __restrict__ Al)
{
  const int t = blockIdx.y;
  const int r = blockIdx.x * 4 + (threadIdx.x >> 6);
  const int lane = threadIdx.x & 63;
  const int fo = (lane & 31) << 2;
  const bool hpart = lane < 32;
  const float* xt = x + (size_t)t * NNODES * F_;
  float4 v;
  if (r < B_) {
    if (hpart) {
      v = *(const float4*)(xt + (size_t)nodes[r] * F_ + fo);
    } else {
      v = make_float4(0.f, 0.f, 0.f, 0.f);
#pragma unroll
      for (int s = 0; s < S1_; ++s) {
        int idx = hop1[t * (B_ * S1_) + r * S1_ + s];
        float4 u = *(const float4*)(xt + (size_t)idx * F_ + fo);
        v.x += u.x; v.y += u.y; v.z += u.z; v.w += u.w;
      }
      v.x /= 5.0f; v.y /= 5.0f; v.z /= 5.0f; v.w /= 5.0f;
    }
  } else {
    const int j = r - B_;
    if (hpart) {
      v = *(const float4*)(xt + (size_t)hop1[t * (B_ * S1_) + j] * F_ + fo);
    } else {
      v = make_float4(0.f, 0.f, 0.f, 0.f);
#pragma unroll
      for (int s = 0; s < S2_; ++s) {
        int idx = hop2[t * (B_ * S1_ * S2_) + j * S2_ + s];
        float4 u = *(const float4*)(xt + (size_t)idx * F_ + fo);
        v.x += u.x; v.y += u.y; v.z += u.z; v.w += u.w;
      }
      v.x *= 0.5f; v.y *= 0.5f; v.z *= 0.5f; v.w *= 0.5f;
    }
  }
  union { f16 h[4]; uint2 u; } H, L;
  float vv[4] = {v.x, v.y, v.z, v.w};
#pragma unroll
  for (int e = 0; e < 4; ++e) {
    f16 hi = (f16)vv[e];
    H.h[e] = hi;
    L.h[e] = (f16)((vv[e] - (float)hi) * 2048.0f);
  }
  const size_t base = ((size_t)t * M1 + r) * K1 + 4 * lane;
  *(uint2*)(Ah + base) = H.u;
  *(uint2*)(Al + base) = L.u;
}

// ---------------------------------------------------------------- GEMM1 (MFMA fp16x3) + spike
// R11/R12 structure (256x128, 8 waves, BK=32, 3-buffer 144KB, paired-sync
// depth-2 pipeline) with CONFLICT-FREE swizzle: chunk kc stored at slot
// kc^((row>>1)&3); read slot kg^((lr>>1)&3). Per-8-lane quantum covers all
// 32 banks exactly (b128 minimum) vs old (lr&3)'s 4-way aliasing.
__global__ __launch_bounds__(512)
void gemm1_mfma(const f16* __restrict__ Ah, const f16* __restrict__ Al,
                const f16* __restrict__ Bth, const f16* __restrict__ Btl,
                unsigned char* __restrict__ Sbase)
{
  // bijective XCD swizzle: 4608 blocks = 8 XCDs x 576.
  const int hid = blockIdx.x + 4 * blockIdx.y + 384 * blockIdx.z;
  const int xcd = hid & 7, ii = hid >> 3;   // ii 0..575
  const int nblk = ii & 3;
  const int pair = xcd * 144 + (ii >> 2);   // 0..1151 = (yblk,z)
  const int yblk = pair % 96;
  const int z    = pair / 96;

  const int t = (z < 8) ? z : 2 * (z - 8);
  const int c = (z < 8) ? 0 : 1;
  const int m0 = yblk * 256;
  const int n0 = nblk * 128;
  const int tid = threadIdx.x;
  const int lane = tid & 63;
  const int w = tid >> 6;                   // 0..7
  const int wr = w >> 1, wc = w & 1;        // wave tile (wr*64, wc*64)

  // buffer = 24576 f16 = 48 KB: Ah rows[0,256) @0, Al @8192, Bh rows[0,128)
  // @16384, Bl @20480 (f16 units). Row stride 32 f16 = 64 B.
  // 16B unit (row,kcs) holds global chunk kc = kcs^((row>>1)&3).
  __shared__ f16 lds[3][24576];             // 144 KB

  const f16* tbAh = Ah  + (size_t)t * M1 * K1;
  const f16* tbAl = Al  + (size_t)t * M1 * K1;
  const f16* tbBh = Bth + (size_t)c * H1_ * K1;
  const f16* tbBl = Btl + (size_t)c * H1_ * K1;

  const f16* srcp[6];
#pragma unroll
  for (int q = 0; q < 6; ++q) {
    const int u = q * 512 + tid;
    const f16* base; int row, grow;
    if (u < 1024)      { base = tbAh; row = u >> 2;          grow = m0 + row; }
    else if (u < 2048) { base = tbAl; row = (u - 1024) >> 2; grow = m0 + row; }
    else if (u < 2560) { base = tbBh; row = (u - 2048) >> 2; grow = n0 + row; }
    else               { base = tbBl; row = (u - 2560) >> 2; grow = n0 + row; }
    const int kc = (u & 3) ^ ((row >> 1) & 3);
    srcp[q] = base + (size_t)grow * K1 + kc * 8;
  }

  auto stage = [&](int buf) {
#pragma unroll
    for (int q = 0; q < 6; ++q) {
      __builtin_amdgcn_global_load_lds(
          (const __attribute__((address_space(1))) void*)srcp[q],
          (__attribute__((address_space(3))) void*)((char*)lds + buf * 49152 + (q * 8 + w) * 1024),
          16, 0, 0);
      srcp[q] += 32;   // next BK=32 chunk
    }
  };

  f32x4 accm[4][4], accc[4][4];
#pragma unroll
  for (int i = 0; i < 4; ++i)
#pragma unroll
    for (int j = 0; j < 4; ++j) {
      accm[i][j] = (f32x4){0.f, 0.f, 0.f, 0.f};
      accc[i][j] = (f32x4){0.f, 0.f, 0.f, 0.f};
    }

  const int kg = lane >> 4;                   // k-group 0..3
  const int lr = lane & 15;
  const int ks = (kg ^ ((lr >> 1) & 3)) * 8;  // conflict-free swizzled slot

  stage(0);
  stage(1);
  __syncthreads();

#pragma unroll
  for (int kt = 0; kt < 8; ++kt) {
    const int cur = kt % 3;
    const f16* bufp = &lds[cur][0];

    f16x8 ah[4], bh[4];
#pragma unroll
    for (int i = 0; i < 4; ++i) ah[i] = *(const f16x8*)(bufp + (wr * 64 + i * 16 + lr) * 32 + ks);
#pragma unroll
    for (int j = 0; j < 4; ++j) bh[j] = *(const f16x8*)(bufp + 16384 + (wc * 64 + j * 16 + lr) * 32 + ks);
    if (kt < 6) stage((kt + 2) % 3);
    __builtin_amdgcn_s_setprio(1);
#pragma unroll
    for (int j = 0; j < 4; ++j)
#pragma unroll
      for (int i = 0; i < 4; ++i)
        accm[i][j] = __builtin_amdgcn_mfma_f32_16x16x32_f16(ah[i], bh[j], accm[i][j], 0, 0, 0);
    __builtin_amdgcn_s_setprio(0);

    f16x8 bl[4];
#pragma unroll
    for (int j = 0; j < 4; ++j) bl[j] = *(const f16x8*)(bufp + 20480 + (wc * 64 + j * 16 + lr) * 32 + ks);
    __builtin_amdgcn_s_setprio(1);
#pragma unroll
    for (int j = 0; j < 4; ++j)
#pragma unroll
      for (int i = 0; i < 4; ++i)
        accc[i][j] = __builtin_amdgcn_mfma_f32_16x16x32_f16(ah[i], bl[j], accc[i][j], 0, 0, 0);
    __builtin_amdgcn_s_setprio(0);

    f16x8 al[4];
#pragma unroll
    for (int i = 0; i < 4; ++i) al[i] = *(const f16x8*)(bufp + 8192 + (wr * 64 + i * 16 + lr) * 32 + ks);
    __builtin_amdgcn_s_setprio(1);
#pragma unroll
    for (int j = 0; j < 4; ++j)
#pragma unroll
      for (int i = 0; i < 4; ++i)
        accc[i][j] = __builtin_amdgcn_mfma_f32_16x16x32_f16(al[i], bh[j], accc[i][j], 0, 0, 0);
    __builtin_amdgcn_s_setprio(0);

    if (kt == 1 || kt == 3 || kt == 5) {
      __syncthreads();
    } else if (kt == 0 || kt == 2 || kt == 4) {
      asm volatile("s_waitcnt lgkmcnt(0)" ::: "memory");
      __builtin_amdgcn_s_barrier();
      __builtin_amdgcn_sched_barrier(0);
    }
  }

  unsigned char* S = Sbase + (size_t)z * M1 * H1_;
#pragma unroll
  for (int i = 0; i < 4; ++i)
#pragma unroll
    for (int j = 0; j < 4; ++j) {
      const int n = n0 + wc * 64 + j * 16 + lr;
#pragma unroll
      for (int r = 0; r < 4; ++r) {
        const int m = m0 + wr * 64 + i * 16 + kg * 4 + r;
        float v = accm[i][j][r] + accc[i][j][r] * 4.8828125e-4f;
        S[(size_t)m * H1_ + n] = (v >= 1.0f) ? 1 : 0;
      }
    }
}

// ---------------------------------------------------------------- GEMM2 fused (S -> A-tile in-kernel) + spike
__global__ __launch_bounds__(256)
void gemm2_fused(const unsigned char* __restrict__ Sbase,
                 const f16* __restrict__ B2h, const f16* __restrict__ B2l,
                 unsigned char* __restrict__ outsbase)
{
  const int z = blockIdx.y;
  const int c = (z < 8) ? 0 : 1;
  const int m0 = blockIdx.x * 128;
  const int tid = threadIdx.x;
  const int lane = tid & 63;
  const int wv = tid >> 6;

  __shared__ f16 lds2[2][8192];   // [buf][A:4096 | Bh:2048 | Bl:2048] f16 = 32 KB

  const unsigned char* Sz = Sbase + (size_t)z * M1 * H1_;
  const f16* Bhc = B2h + (size_t)c * H2_ * 1024;
  const f16* Blc = B2l + (size_t)c * H2_ * 1024;

  const f16* srcB[2];
#pragma unroll
  for (int q = 0; q < 2; ++q) {
    const int v = q * 256 + tid;              // 0..511
    if (v < 256) {
      const int k8 = v >> 6, row = v & 63;
      srcB[q] = Bhc + (size_t)row * 1024 + k8 * 8;
    } else {
      const int v2 = v - 256, k8 = v2 >> 6, row = v2 & 63;
      srcB[q] = Blc + (size_t)row * 1024 + k8 * 8;
    }
  }
  auto stageB = [&](int buf) {
#pragma unroll
    for (int q = 0; q < 2; ++q) {
      __builtin_amdgcn_global_load_lds(
          (const __attribute__((address_space(1))) void*)srcB[q],
          (__attribute__((address_space(3))) void*)((char*)lds2 + buf * 16384 + 8192 + q * 4096 + wv * 1024),
          16, 0, 0);
      srcB[q] += 32;
    }
  };

  const int arow = tid >> 1;       // 0..127
  const int ahalf = tid & 1;
  const int k8b = ahalf * 2;

  auto loadS = [&](int kt, uint4* regs) {
    if (kt < 16) {
      regs[0] = *(const uint4*)(Sz + (size_t)(m0 + arow) * H1_ + kt * 32 + ahalf * 16);
    } else {
      const int k0 = (kt - 16) * 32 + ahalf * 16;
#pragma unroll
      for (int s = 0; s < S1_; ++s)
        regs[s] = *(const uint4*)(Sz + ((size_t)B_ + (size_t)(m0 + arow) * S1_ + s) * H1_ + k0);
    }
  };
  auto writeA = [&](int buf, int kt, const uint4* regs) {
    uint4 b;
    if (kt < 16) {
      b = regs[0];
    } else {
      b.x = regs[0].x + regs[1].x + regs[2].x + regs[3].x + regs[4].x;
      b.y = regs[0].y + regs[1].y + regs[2].y + regs[3].y + regs[4].y;
      b.z = regs[0].z + regs[1].z + regs[2].z + regs[3].z + regs[4].z;
      b.w = regs[0].w + regs[1].w + regs[2].w + regs[3].w + regs[4].w;
    }
    union { uint4 v; unsigned char by[16]; } U; U.v = b;
    union { f16 h[8]; uint4 v; } P0, P1;
#pragma unroll
    for (int e = 0; e < 8; ++e) {
      P0.h[e] = (f16)(int)U.by[e];
      P1.h[e] = (f16)(int)U.by[8 + e];
    }
    f16* dst = &lds2[buf][0];
    *(uint4*)(dst + ((size_t)k8b * 128 + arow) * 8)       = P0.v;
    *(uint4*)(dst + ((size_t)(k8b + 1) * 128 + arow) * 8) = P1.v;
  };

  f32x4 acch[2][4], accl[2][4];
#pragma unroll
  for (int i = 0; i < 2; ++i)
#pragma unroll
    for (int j = 0; j < 4; ++j) {
      acch[i][j] = (f32x4){0.f, 0.f, 0.f, 0.f};
      accl[i][j] = (f32x4){0.f, 0.f, 0.f, 0.f};
    }

  const int kg = lane >> 4;
  const int lr = lane & 15;

  {
    uint4 regs[5];
    loadS(0, regs);
    stageB(0);
    writeA(0, 0, regs);
  }
  __syncthreads();

#pragma unroll 1
  for (int kt = 0; kt < 32; ++kt) {
    const int cur = kt & 1;
    uint4 regs[5];
    if (kt < 31) {
      stageB(cur ^ 1);
      loadS(kt + 1, regs);
    }

    f16x8 a[2];
#pragma unroll
    for (int i = 0; i < 2; ++i)
      a[i] = *(const f16x8*)&lds2[cur][(size_t)(kg * 128 + wv * 32 + i * 16 + lr) * 8];
#pragma unroll
    for (int j = 0; j < 4; ++j) {
      f16x8 bh = *(const f16x8*)&lds2[cur][4096 + (size_t)(kg * 64 + j * 16 + lr) * 8];
      f16x8 bl = *(const f16x8*)&lds2[cur][6144 + (size_t)(kg * 64 + j * 16 + lr) * 8];
#pragma unroll
      for (int i = 0; i < 2; ++i) {
        acch[i][j] = __builtin_amdgcn_mfma_f32_16x16x32_f16(a[i], bh, acch[i][j], 0, 0, 0);
        accl[i][j] = __builtin_amdgcn_mfma_f32_16x16x32_f16(a[i], bl, accl[i][j], 0, 0, 0);
      }
    }
    if (kt < 31) writeA(cur ^ 1, kt + 1, regs);
    __syncthreads();
  }

  unsigned char* outs = outsbase + (size_t)z * B_ * H2_;
#pragma unroll
  for (int i = 0; i < 2; ++i)
#pragma unroll
    for (int j = 0; j < 4; ++j) {
      const int n = j * 16 + lr;
#pragma unroll
      for (int r = 0; r < 4; ++r) {
        const int m = m0 + wv * 32 + i * 16 + kg * 4 + r;
        float v = acch[i][j][r] + accl[i][j][r] * 4.8828125e-4f;
        outs[(size_t)m * H2_ + n] = (v >= 1.0f) ? 1 : 0;
      }
    }
}

// ---------------------------------------------------------------- attention + head
__global__ __launch_bounds__(256)
void final_kernel(const unsigned char* __restrict__ outsbase,
                  const float* __restrict__ postab,
                  const float* __restrict__ apw, const float* __restrict__ apb,
                  const float* __restrict__ anw, const float* __restrict__ anb,
                  const float* __restrict__ mtgw, const float* __restrict__ mtgb,
                  float* __restrict__ out)
{
  const int b = blockIdx.x * 4 + (threadIdx.x >> 6);
  const int lane = threadIdx.x & 63;
  float stacked = 0.f;
#pragma unroll
  for (int c = 0; c < 2; ++c) {
    const int Tc = c ? 4 : 8;
    const int zb = c ? 8 : 0;
    const float wp = apw[c * H2_ + lane];
    const float wn = anw[c * H2_ + lane];
    float seqv[8], sp[8], sn[8];
#pragma unroll
    for (int tt = 0; tt < Tc; ++tt) {
      const float sv = (float)outsbase[((size_t)(zb + tt) * B_ + b) * H2_ + lane];
      seqv[tt] = sv;
      sp[tt] = wsum64((sv + postab[tt * H2_ + lane]) * wp);
      sn[tt] = wsum64(sv * wn);
    }
    const float bp = apb[c], bn = anb[c];
    float mp = -3.4e38f, mn = -3.4e38f;
#pragma unroll
    for (int tt = 0; tt < Tc; ++tt) {
      sp[tt] += bp; sn[tt] += bn;
      mp = fmaxf(mp, sp[tt]); mn = fmaxf(mn, sn[tt]);
    }
    float ep[8], en[8], sump = 0.f, sumn = 0.f;
#pragma unroll
    for (int tt = 0; tt < Tc; ++tt) {
      ep[tt] = expf(sp[tt] - mp);
      en[tt] = expf(sn[tt] - mn);
      sump += ep[tt]; sumn += en[tt];
    }
    float embp = 0.f, embn = 0.f;
#pragma unroll
    for (int tt = 0; tt < Tc; ++tt) {
      embp += (seqv[tt] + postab[tt * H2_ + lane]) * (ep[tt] / sump);
      embn += seqv[tt] * (en[tt] / sumn);
    }
    stacked += 0.5f * (0.6f * embp + 0.4f * embn);
  }
  float res = 0.f;
#pragma unroll
  for (int o = 0; o < O_; ++o) {
    float r = wsum64(stacked * mtgw[lane * O_ + o]);
    if (lane == o) res = r;
  }
  if (lane < O_) out[(size_t)b * O_ + lane] = res + mtgb[lane];
}

// ---------------------------------------------------------------- launch
extern "C" void kernel_launch(void* const* d_in, const int* in_sizes, int n_in,
                              void* d_out, int out_size, void* d_ws, size_t ws_size,
                              hipStream_t stream)
{
  const int*   nodes  = (const int*)d_in[0];
  const int*   hop1   = (const int*)d_in[1];
  const int*   hop2   = (const int*)d_in[2];
  const float* x      = (const float*)d_in[3];
  const float* Wself1 = (const float*)d_in[4];
  const float* Wnbr1  = (const float*)d_in[5];
  const float* Wself2 = (const float*)d_in[6];
  const float* Wnbr2  = (const float*)d_in[7];
  const float* apw    = (const float*)d_in[8];
  const float* apb    = (const float*)d_in[9];
  const float* anw    = (const float*)d_in[10];
  const float* anb    = (const float*)d_in[11];
  const float* mtgw   = (const float*)d_in[12];
  const float* mtgb   = (const float*)d_in[13];
  float* out = (float*)d_out;

  char* ws = (char*)d_ws;
  size_t off = 0;
  float* postab = (float*)(ws + off);               off += 4096;
  f16* Ahb = (f16*)(ws + off);                      off += (size_t)T_ * M1 * K1 * 2;  // 100.66 MB
  f16* Alb = (f16*)(ws + off);                      off += (size_t)T_ * M1 * K1 * 2;  // 100.66 MB
  unsigned char* Sbase = (unsigned char*)(ws + off); off += (size_t)NZ * M1 * H1_;    // 151.0 MB
  unsigned char* outsb = (unsigned char*)(ws + off); off += (size_t)NZ * B_ * H2_;    //   3.1 MB
  if (ws_size < off) return;

  // stream-ordered aliases:
  //  - gemm1 B limbs live in outsb until gemm2 overwrites outs (1.0 MB < 3.1 MB)
  //  - B2t limbs (512 KB) reuse Alb after gemm1 (prep_w2 launches after gemm1)
  f16* Bth = (f16*)outsb;
  f16* Btl = Bth + (size_t)2 * H1_ * K1;
  f16* B2h = Alb;
  f16* B2l = B2h + (size_t)2 * H2_ * 1024;

  hipLaunchKernelGGL(postab_kernel, dim3(1), dim3(512), 0, stream, postab);
  hipLaunchKernelGGL(prep_w, dim3(1024), dim3(256), 0, stream, Wself1, Wnbr1, Bth, Btl);
  hipLaunchKernelGGL(gather_kernel, dim3(M1 / 4, T_), dim3(256), 0, stream,
                     nodes, hop1, hop2, x, Ahb, Alb);
  hipLaunchKernelGGL(gemm1_mfma, dim3(4, 96, NZ), dim3(512), 0, stream,
                     Ahb, Alb, Bth, Btl, Sbase);
  hipLaunchKernelGGL(prep_w2, dim3(128), dim3(256), 0, stream, Wself2, Wnbr2, B2h, B2l);
  hipLaunchKernelGGL(gemm2_fused, dim3(B_ / 128, NZ), dim3(256), 0, stream,
                     Sbase, B2h, B2l, outsb);
  hipLaunchKernelGGL(final_kernel, dim3(B_ / 4), dim3(256), 0, stream,
                     outsb, postab, apw, apb, anw, anb, mtgw, mtgb, out);
}